// Round 4
// baseline (787.928 us; speedup 1.0000x reference)
//
#include <hip/hip_runtime.h>

#define E_EDGES 131072
#define D_IN 128
#define D_HID 512
#define D_OUT 128

typedef __bf16 bf16x8 __attribute__((ext_vector_type(8)));
typedef float f32x4 __attribute__((ext_vector_type(4)));

// round-to-nearest-even f32 -> bf16 bits
__device__ __forceinline__ unsigned short f2bf(float f) {
    unsigned int u = __float_as_uint(f);
    unsigned int r = (u + 0x7FFFu + ((u >> 16) & 1u)) >> 16;
    return (unsigned short)r;
}

__global__ void zero_kernel(int* __restrict__ cnt) {
    int i = blockIdx.x * blockDim.x + threadIdx.x;   // 32768 threads, int4 each
    ((int4*)cnt)[i] = make_int4(0, 0, 0, 0);
}

__global__ void hist_kernel(const int* __restrict__ seg, int* __restrict__ cnt, int nnz) {
    int i = blockIdx.x * blockDim.x + threadIdx.x;
    if (i * 4 < nnz) {
        int4 s = ((const int4*)seg)[i];
        atomicAdd(&cnt[s.x], 1);
        atomicAdd(&cnt[s.y], 1);
        atomicAdd(&cnt[s.z], 1);
        atomicAdd(&cnt[s.w], 1);
    }
}

// 128 blocks x 256 threads; block b sums cnt ints [b*1024, b*1024+1023]
__global__ void blocksum_kernel(const int* __restrict__ cnt, int* __restrict__ bsum) {
    __shared__ int wsum[4];
    const int b = blockIdx.x, t = threadIdx.x;
    int4 c = ((const int4*)cnt)[b * 256 + t];
    int s = c.x + c.y + c.z + c.w;
    for (int d = 32; d; d >>= 1) s += __shfl_down(s, d);
    if ((t & 63) == 0) wsum[t >> 6] = s;
    __syncthreads();
    if (t == 0) bsum[b] = wsum[0] + wsum[1] + wsum[2] + wsum[3];
}

// 1 wave: exclusive-scan 128 block sums; also writes off[E_EDGES] = total
__global__ void bscan_kernel(const int* __restrict__ bsum, int* __restrict__ bpre,
                             int* __restrict__ off_last) {
    const int l = threadIdx.x;   // 0..63
    int a = bsum[2 * l], b = bsum[2 * l + 1];
    int s = a + b;
    for (int d = 1; d < 64; d <<= 1) {
        int u = __shfl_up(s, d);
        if (l >= d) s += u;
    }
    int excl = s - (a + b);
    bpre[2 * l] = excl;
    bpre[2 * l + 1] = excl + a;
    if (l == 63) off_last[0] = s;
}

// 128 blocks x 256 threads; rescan each 1024-chunk with block prefix; coalesced int4
__global__ void scan2_kernel(const int* __restrict__ cnt, const int* __restrict__ bpre,
                             int* __restrict__ off, int* __restrict__ cur) {
    __shared__ int wsum[4];
    const int b = blockIdx.x, t = threadIdx.x;
    const int gid = b * 256 + t;
    int4 c = ((const int4*)cnt)[gid];
    const int s = c.x + c.y + c.z + c.w;
    const int lane = t & 63, w = t >> 6;
    int incl = s;
    for (int d = 1; d < 64; d <<= 1) {
        int u = __shfl_up(incl, d);
        if (lane >= d) incl += u;
    }
    if (lane == 63) wsum[w] = incl;
    __syncthreads();
    int woff = 0;
    for (int i = 0; i < w; ++i) woff += wsum[i];
    const int base = bpre[b] + woff + (incl - s);
    int4 o;
    o.x = base;
    o.y = base + c.x;
    o.z = base + c.x + c.y;
    o.w = base + c.x + c.y + c.z;
    ((int4*)off)[gid] = o;
    ((int4*)cur)[gid] = o;
}

__global__ void fill_kernel(const int* __restrict__ seg, int* __restrict__ cur,
                            int* __restrict__ csr, int nnz) {
    int i = blockIdx.x * blockDim.x + threadIdx.x;
    if (i * 4 < nnz) {
        int4 s = ((const int4*)seg)[i];
        int p0 = atomicAdd(&cur[s.x], 1);
        int p1 = atomicAdd(&cur[s.y], 1);
        int p2 = atomicAdd(&cur[s.z], 1);
        int p3 = atomicAdd(&cur[s.w], 1);
        csr[p0] = i * 4;
        csr[p1] = i * 4 + 1;
        csr[p2] = i * 4 + 2;
        csr[p3] = i * 4 + 3;
    }
}

// W1 [128][512] fp32 -> w1b = bf16 W1^T [512][128]; W2 [512][128] -> w2b [128][512]
__global__ void convw_kernel(const float* __restrict__ W1, const float* __restrict__ W2,
                             unsigned short* __restrict__ w1b, unsigned short* __restrict__ w2b) {
    int i = blockIdx.x * blockDim.x + threadIdx.x;
    if (i < D_IN * D_HID) {
        int n = i >> 7, k = i & 127;                 // w1b[n][k]
        w1b[i] = f2bf(W1[(size_t)k * D_HID + n]);
    } else {
        int i2 = i - D_IN * D_HID;
        int n = i2 >> 9, k = i2 & 511;               // w2b[n][k]
        w2b[i2] = f2bf(W2[(size_t)k * D_OUT + n]);
    }
}

// Gather-mean: lean kernel, high occupancy. 4 waves/block, wave owns 16 edges.
// Lanes 0-31 / 32-63 each handle one row of a row-pair (rr), 16B per lane.
// Writes bf16 mean matrix [E][128] row-major to meanb.
__global__ __launch_bounds__(256) void gather_kernel(
    const float* __restrict__ x, const int* __restrict__ csr,
    const int* __restrict__ off, unsigned short* __restrict__ meanb)
{
    const int tid  = threadIdx.x;
    const int lane = tid & 63;
    const int w    = tid >> 6;
    const int tile = blockIdx.x;      // 0..2047
    const int row0 = w * 16;

    const int c  = lane & 31;         // float4 column (cols 4c..4c+3)
    const int rr = lane >> 5;         // row parity within pair
    const char* xb = (const char*)x + c * 16;

    // preload the 17 offsets this wave needs
    int oreg = off[tile * 64 + row0 + (lane < 17 ? lane : 16)];

    for (int el = 0; el < 16; ++el) {
        const int row = row0 + el;
        const int beg = __shfl(oreg, el);
        const int end = __shfl(oreg, el + 1);
        const int n = end - beg;
        const int* ce = csr + beg;
        f32x4 a0 = {0.f, 0.f, 0.f, 0.f};
        f32x4 a1 = a0, a2 = a0, a3 = a0, a4 = a0, a5 = a0, a6 = a0, a7 = a0;
        // single strip loop, 16 rows per iteration, per-lane predicated loads:
        // no tail, no OOB, n==0 safe.
        for (int j = 0; j < n; j += 16) {
#define GSLOT(k, acc)                                                        \
            {                                                                \
                const int jj = j + 2 * (k) + rr;                             \
                if (jj < n) {                                                \
                    const int idx = ce[jj];                                  \
                    f32x4 v = __builtin_nontemporal_load(                    \
                        (const f32x4*)(xb + (size_t)idx * 512));             \
                    acc += v;                                                \
                }                                                            \
            }
            GSLOT(0, a0) GSLOT(1, a1) GSLOT(2, a2) GSLOT(3, a3)
            GSLOT(4, a4) GSLOT(5, a5) GSLOT(6, a6) GSLOT(7, a7)
#undef GSLOT
        }
        f32x4 tot = ((a0 + a1) + (a2 + a3)) + ((a4 + a5) + (a6 + a7));
        tot[0] += __shfl_xor(tot[0], 32);
        tot[1] += __shfl_xor(tot[1], 32);
        tot[2] += __shfl_xor(tot[2], 32);
        tot[3] += __shfl_xor(tot[3], 32);
        const float scale = 1.0f / (float)(n > 0 ? n : 1);
        if (lane < 32) {
            unsigned int d0 = (unsigned)f2bf(tot[0] * scale) | ((unsigned)f2bf(tot[1] * scale) << 16);
            unsigned int d1 = (unsigned)f2bf(tot[2] * scale) | ((unsigned)f2bf(tot[3] * scale) << 16);
            *(uint2*)((char*)meanb + (size_t)row * 256 + (size_t)tile * 16384 + c * 8) =
                make_uint2(d0, d1);
        }
    }
}

// GEMM: meanb[E][128] bf16 -> (@W1+b1, relu) -> (@W2+b2) -> out fp32.
// block = 256 threads (4 waves); wave owns 16 rows; tile = 64 rows.
__global__ __launch_bounds__(256) void gemm_kernel(
    const unsigned short* __restrict__ meanb, const unsigned short* __restrict__ w1b,
    const unsigned short* __restrict__ w2b, const float* __restrict__ b1,
    const float* __restrict__ b2, float* __restrict__ out)
{
    __shared__ unsigned short hslice[4][16 * 32];   // per-wave h K-slice, 4 KB

    const int tid  = threadIdx.x;
    const int lane = tid & 63;
    const int w    = tid >> 6;
    const int tile = blockIdx.x;
    const int row0 = w * 16;

    const int lrow = lane & 15;
    const int lgrp = lane >> 4;

    // A fragments straight from global meanb (row-major, 64B-line aligned reads)
    bf16x8 afrag[4];
#pragma unroll
    for (int kk = 0; kk < 4; ++kk) {
        const int row = tile * 64 + row0 + lrow;
        afrag[kk] = *(const bf16x8*)(meanb + (size_t)row * 128 + kk * 32 + lgrp * 8);
    }

    const f32x4 fzero = {0.f, 0.f, 0.f, 0.f};
    f32x4 acc2[8];
#pragma unroll
    for (int t = 0; t < 8; ++t) acc2[t] = fzero;

    unsigned short* hs = &hslice[w][0];

    for (int ntp = 0; ntp < 16; ++ntp) {
#pragma unroll
        for (int half = 0; half < 2; ++half) {
            const int nt = ntp * 2 + half;
            f32x4 acc = fzero;
#pragma unroll
            for (int kk = 0; kk < 4; ++kk) {
                const bf16x8 b = *(const bf16x8*)(w1b + (size_t)(nt * 16 + lrow) * 128 + kk * 32 + lgrp * 8);
                acc = __builtin_amdgcn_mfma_f32_16x16x32_bf16(afrag[kk], b, acc, 0, 0, 0);
            }
            const int hcol = nt * 16 + lrow;
            const float bias = b1[hcol];
#pragma unroll
            for (int r = 0; r < 4; ++r) {
                float v = acc[r] + bias;
                v = fmaxf(v, 0.f);
                const int rowD = lgrp * 4 + r;
                const int klocal = half * 16 + lrow;
                unsigned int byte = ((unsigned)(rowD * 64 + klocal * 2)) ^ ((unsigned)(rowD & 3) << 4);
                *(unsigned short*)((char*)hs + byte) = f2bf(v);
            }
        }
        // consume the 16x32 h slice as GEMM2 A-fragment (K-slice ntp)
        {
            unsigned int byte = ((unsigned)(lrow * 64 + lgrp * 16)) ^ ((unsigned)(lrow & 3) << 4);
            const bf16x8 a2 = *(const bf16x8*)((const char*)hs + byte);
#pragma unroll
            for (int nt2 = 0; nt2 < 8; ++nt2) {
                const bf16x8 b = *(const bf16x8*)(w2b + (size_t)(nt2 * 16 + lrow) * 512 + ntp * 32 + lgrp * 8);
                acc2[nt2] = __builtin_amdgcn_mfma_f32_16x16x32_bf16(a2, b, acc2[nt2], 0, 0, 0);
            }
        }
    }

#pragma unroll
    for (int nt2 = 0; nt2 < 8; ++nt2) {
        const int col = nt2 * 16 + lrow;
        const float bias = b2[col];
#pragma unroll
        for (int r = 0; r < 4; ++r) {
            const int row = tile * 64 + row0 + lgrp * 4 + r;
            out[(size_t)row * 128 + col] = acc2[nt2][r] + bias;
        }
    }
}

extern "C" void kernel_launch(void* const* d_in, const int* in_sizes, int n_in,
                              void* d_out, int out_size, void* d_ws, size_t ws_size,
                              hipStream_t stream)
{
    const float* x  = (const float*)d_in[0];
    const int* hyper = (const int*)d_in[1];
    const float* W1 = (const float*)d_in[2];
    const float* b1 = (const float*)d_in[3];
    const float* W2 = (const float*)d_in[4];
    const float* b2 = (const float*)d_in[5];
    const int nnz = in_sizes[0] / D_IN;
    const int* seg = hyper + nnz;   // hyperedge_index[1]

    // workspace map (non-overlapping; off needs E+1 ints):
    char* ws = (char*)d_ws;
    int* cnt  = (int*)(ws + 0x000000);           // E ints
    int* off  = (int*)(ws + 0x080000);           // E+1 ints
    int* cur  = (int*)(ws + 0x100100);           // E ints
    int* csr  = (int*)(ws + 0x180100);           // NNZ ints (8 MB)
    unsigned short* w1b = (unsigned short*)(ws + 0x980100);  // 128 KB
    unsigned short* w2b = (unsigned short*)(ws + 0x9A0100);  // 128 KB
    int* bsum = (int*)(ws + 0x9C0100);           // 128 ints
    int* bpre = (int*)(ws + 0x9C0300);           // 128 ints
    unsigned short* meanb = (unsigned short*)(ws + 0xA00000);  // E x 128 bf16 = 32 MB
    float* out = (float*)d_out;

    hipLaunchKernelGGL(zero_kernel, dim3(128), dim3(256), 0, stream, cnt);
    hipLaunchKernelGGL(hist_kernel, dim3(nnz / 1024), dim3(256), 0, stream, seg, cnt, nnz);
    hipLaunchKernelGGL(blocksum_kernel, dim3(128), dim3(256), 0, stream, cnt, bsum);
    hipLaunchKernelGGL(bscan_kernel, dim3(1), dim3(64), 0, stream, bsum, bpre, off + E_EDGES);
    hipLaunchKernelGGL(scan2_kernel, dim3(128), dim3(256), 0, stream, cnt, bpre, off, cur);
    hipLaunchKernelGGL(fill_kernel, dim3(nnz / 1024), dim3(256), 0, stream, seg, cur, csr, nnz);
    hipLaunchKernelGGL(convw_kernel, dim3((D_IN * D_HID + D_HID * D_OUT) / 256), dim3(256), 0,
                       stream, W1, W2, w1b, w2b);
    hipLaunchKernelGGL(gather_kernel, dim3(E_EDGES / 64), dim3(256), 0, stream,
                       x, csr, off, meanb);
    hipLaunchKernelGGL(gemm_kernel, dim3(E_EDGES / 64), dim3(256), 0, stream,
                       meanb, w1b, w2b, b1, b2, out);
}